// Round 1
// baseline (597.311 us; speedup 1.0000x reference)
//
#include <hip/hip_runtime.h>
#include <math.h>

#define NTOK   32768
#define DDIM   2048
#define NEXP   64
#define TOKB   64             // tokens per block
#define BLOCK  256            // 4 waves
#define TW     16             // tokens per wave
#define NTI    4              // tokens per group (i)
#define NE     4              // experts per lane (e)

// extract component dd (compile-time) from a float4 without memory round-trip
#define XGET(v, dd) ((dd) == 0 ? (v).x : (dd) == 1 ? (v).y : (dd) == 2 ? (v).z : (v).w)

// 64 FMAs of one j4 (4 d-values): acc[q][i][e] += x[i][dd] * w[dd][e]
// per-chain order: ascending d within quarter -> bitwise-identical to validated kernel
#define FMA_STEP(q, XP, WC)                                             \
    _Pragma("unroll")                                                   \
    for (int dd = 0; dd < 4; ++dd) {                                    \
        _Pragma("unroll")                                               \
        for (int i = 0; i < NTI; ++i) {                                 \
            const float xv = XGET(XP[i], dd);                           \
            acc[q][i][0] = fmaf(xv, WC[dd].x, acc[q][i][0]);            \
            acc[q][i][1] = fmaf(xv, WC[dd].y, acc[q][i][1]);            \
            acc[q][i][2] = fmaf(xv, WC[dd].z, acc[q][i][2]);            \
            acc[q][i][3] = fmaf(xv, WC[dd].w, acc[q][i][3]);            \
        }                                                               \
    }

// one j4 step at ring slot p: prefetch W(j4+1)->WN, compute with XP/WC,
// then reload XP with x(j4+4) (slot consumed again 4 steps from now)
#define STEP(q, p, XP, WC, WN, PFW, PFX)                                \
    if (PFW) {                                                          \
        _Pragma("unroll")                                               \
        for (int dd = 0; dd < 4; ++dd)                                  \
            WN[dd] = *(const float4*)(wq + (((p) + 1) * 4 + dd) * NEXP);\
    }                                                                   \
    FMA_STEP(q, XP, WC)                                                 \
    if (PFX) {                                                          \
        _Pragma("unroll")                                               \
        for (int i = 0; i < NTI; ++i)                                   \
            XP[i] = *(const float4*)(xq + i * DDIM + ((p) * 4 + 16));   \
    }

__global__ __launch_bounds__(BLOCK, 2)
void router_kernel(const float* __restrict__ x, const float* __restrict__ wde,
                   float* __restrict__ out) {
    __shared__ float lgs[TOKB][NEXP + 1];   // stride 65: conflict-free gather

    const int tid  = threadIdx.x;
    const int lane = tid & 63;
    const int w    = tid >> 6;
    const int g    = lane >> 4;             // token group 0..3
    const int el   = lane & 15;             // expert-quad lane: experts el*4..el*4+3
    const int tl0  = w * TW + g * NTI;      // lane's first local token
    const int tok0 = blockIdx.x * TOKB;

    const float* xq = x + (size_t)(tok0 + tl0) * DDIM;  // token i adds i*DDIM
    const float* wq = wde + el * 4;                     // row d adds d*NEXP

    // 4 independent quarter accumulators (validated combine order at the end)
    float acc[4][NTI][NE];
    #pragma unroll
    for (int q = 0; q < 4; ++q)
        #pragma unroll
        for (int i = 0; i < NTI; ++i)
            #pragma unroll
            for (int e = 0; e < NE; ++e) acc[q][i][e] = 0.0f;

    // x ring (depth 4 j4s) and w ring (depth 2 j4s), all statically indexed
    float4 X0[NTI], X1[NTI], X2[NTI], X3[NTI];
    float4 WA[4], WB[4];

    #pragma unroll
    for (int i = 0; i < NTI; ++i) {
        X0[i] = *(const float4*)(xq + i * DDIM + 0);
        X1[i] = *(const float4*)(xq + i * DDIM + 4);
        X2[i] = *(const float4*)(xq + i * DDIM + 8);
        X3[i] = *(const float4*)(xq + i * DDIM + 12);
    }
    #pragma unroll
    for (int dd = 0; dd < 4; ++dd)
        WA[dd] = *(const float4*)(wq + dd * NEXP);

    // main loop: 512 j4 steps, no LDS, no barriers
    #pragma unroll
    for (int q = 0; q < 4; ++q) {
        const int jbN = (q == 3) ? 31 : 32;    // peel last jb of q3 as tail
        for (int jb = 0; jb < jbN; ++jb) {
            STEP(q, 0, X0, WA, WB, true, true)
            STEP(q, 1, X1, WB, WA, true, true)
            STEP(q, 2, X2, WA, WB, true, true)
            STEP(q, 3, X3, WB, WA, true, true)
            xq += 16;            // 16 d per jb
            wq += 16 * NEXP;
        }
    }
    // tail: j4 = 508..511 — no x prefetch; w prefetch up to d=2047 only
    STEP(3, 0, X0, WA, WB, true,  false)
    STEP(3, 1, X1, WB, WA, true,  false)
    STEP(3, 2, X2, WA, WB, true,  false)
    STEP(3, 3, X3, WB, WA, false, false)

    // combine quarters exactly like the validated kernel: (q0+q1)+(q2+q3)
    #pragma unroll
    for (int i = 0; i < NTI; ++i) {
        #pragma unroll
        for (int e = 0; e < NE; ++e) {
            float a01 = acc[0][i][e] + acc[1][i][e];
            float a23 = acc[2][i][e] + acc[3][i][e];
            lgs[tl0 + i][el * 4 + e] = a01 + a23;
        }
    }
    __syncthreads();

    if (tid < 64) {
        const int tok = tok0 + tid;
        float lg[NEXP];
        #pragma unroll
        for (int e = 0; e < NEXP; ++e) lg[e] = lgs[tid][e];

        // softmax over 64 experts (fp32, max-subtracted)
        float m = lg[0];
        #pragma unroll
        for (int e = 1; e < NEXP; ++e) m = fmaxf(m, lg[e]);
        float s = 0.0f;
        #pragma unroll
        for (int e = 0; e < NEXP; ++e) { lg[e] = expf(lg[e] - m); s += lg[e]; }

        // top-8, strict '>' keeps lowest index on ties (lax.top_k semantics)
        unsigned long long chosen = 0ull;
        float wv[8], wi[8];
        #pragma unroll
        for (int k = 0; k < 8; ++k) {
            float best = -1.0f; int bi = 0;
            #pragma unroll
            for (int e = 0; e < NEXP; ++e) {
                bool ok = (((chosen >> e) & 1ull) == 0ull) && (lg[e] > best);
                best = ok ? lg[e] : best;
                bi   = ok ? e : bi;
            }
            chosen |= (1ull << bi);
            wv[k] = best;
            wi[k] = (float)bi;
        }

        // second softmax over the 8 selected gating probabilities
        float p0 = wv[0] / s;
        float e2[8]; float s2 = 0.0f;
        #pragma unroll
        for (int k = 0; k < 8; ++k) { e2[k] = expf(wv[k] / s - p0); s2 += e2[k]; }

        float4* ow = (float4*)(out + (size_t)tok * 8);
        ow[0] = make_float4(e2[0]/s2, e2[1]/s2, e2[2]/s2, e2[3]/s2);
        ow[1] = make_float4(e2[4]/s2, e2[5]/s2, e2[6]/s2, e2[7]/s2);
        float4* oi = (float4*)(out + (size_t)NTOK * 8 + (size_t)tok * 8);
        oi[0] = make_float4(wi[0], wi[1], wi[2], wi[3]);
        oi[1] = make_float4(wi[4], wi[5], wi[6], wi[7]);
    }
}

extern "C" void kernel_launch(void* const* d_in, const int* in_sizes, int n_in,
                              void* d_out, int out_size, void* d_ws, size_t ws_size,
                              hipStream_t stream) {
    const float* x   = (const float*)d_in[0];
    const float* wde = (const float*)d_in[1];
    float* out       = (float*)d_out;
    router_kernel<<<dim3(NTOK / TOKB), dim3(BLOCK), 0, stream>>>(x, wde, out);
}